// Round 5
// baseline (320.981 us; speedup 1.0000x reference)
//
#include <hip/hip_runtime.h>

#define SLEN 8192
#define DIN  512

typedef short bf16x8 __attribute__((ext_vector_type(8)));
typedef float f32x4  __attribute__((ext_vector_type(4)));
typedef float f32x16 __attribute__((ext_vector_type(16)));
typedef unsigned int u32x4 __attribute__((ext_vector_type(4)));
typedef unsigned int u32x2 __attribute__((ext_vector_type(2)));

__device__ __forceinline__ unsigned short f2bf(float f) {
  unsigned int u = __float_as_uint(f);
  u += 0x7FFFu + ((u >> 16) & 1u);           // RNE
  return (unsigned short)(u >> 16);
}
__device__ __forceinline__ float bf2f(unsigned short h) {
  return __uint_as_float(((unsigned int)h) << 16);
}
__device__ __forceinline__ unsigned int cvtpk(float lo, float hi) {
  unsigned int r;
  asm volatile("v_cvt_pk_bf16_f32 %0, %1, %2" : "=v"(r) : "v"(lo), "v"(hi));
  return r;
}

#define MFMA16(a, b, c) __builtin_amdgcn_mfma_f32_16x16x32_bf16((a), (b), (c), 0, 0, 0)
#define MFMA32(a, b, c) __builtin_amdgcn_mfma_f32_32x32x16_bf16((a), (b), (c), 0, 0, 0)

// XOR swizzle for [row][128B] LDS tiles
__device__ __forceinline__ int SW(int row, int off) {
  return row * 128 + (off ^ ((row & 7) << 4));
}

// ------- B: split + transpose W -> Wt[n][k], n: 0-63 Q(scaled), 64-127 K, 128-191 V -------
__global__ __launch_bounds__(256) void k_splitw(const float* __restrict__ Wq,
                                                const float* __restrict__ Wk,
                                                const float* __restrict__ Wv,
                                                unsigned short* __restrict__ Wth,
                                                unsigned short* __restrict__ Wtl) {
  int idx = blockIdx.x * 256 + threadIdx.x;  // n*512 + k, 98304 total
  int n = idx >> 9, k = idx & 511;
  float w;
  if (n < 64)       w = Wq[k * 64 + n] * 0.18033688011112042f;  // log2(e)/8 folded in
  else if (n < 128) w = Wk[k * 64 + (n - 64)];
  else              w = Wv[k * 64 + (n - 128)];
  unsigned short h = f2bf(w);
  Wth[idx] = h;
  Wtl[idx] = f2bf(w - bf2f(h));
}

// ---------------- C: QKV = x @ [Wq|Wk|Wv], x read ONCE, 16-row m-tiles ----------------
__global__ __launch_bounds__(256) void k_qkv(const float* __restrict__ x,
                                             const unsigned short* __restrict__ Wth,
                                             const unsigned short* __restrict__ Wtl,
                                             unsigned short* __restrict__ Qh,
                                             unsigned short* __restrict__ Ql,
                                             unsigned short* __restrict__ Kh,
                                             unsigned short* __restrict__ Kl,
                                             unsigned short* __restrict__ Vt) {
  const int tid = threadIdx.x;
  const int wave = tid >> 6, lane = tid & 63;
  const int c = lane & 15, g = lane >> 4;
  const int mbase = blockIdx.x * 16;              // 512 m-tiles of 16 rows
  const int nt0 = wave * 3;                       // each wave: 3 of 12 n-tiles

  const int rowA = mbase + c;                     // all waves share rows (L1 broadcast)
  f32x4 acc[3];
  for (int j = 0; j < 3; ++j) acc[j] = (f32x4){0.f, 0.f, 0.f, 0.f};

  for (int k0 = 0; k0 < DIN; k0 += 32) {
    const float* xp = x + (size_t)rowA * DIN + k0 + g * 8;
    float4 f0 = *reinterpret_cast<const float4*>(xp);
    float4 f1 = *reinterpret_cast<const float4*>(xp + 4);
    float fv[8] = {f0.x, f0.y, f0.z, f0.w, f1.x, f1.y, f1.z, f1.w};
    bf16x8 ah, al;
#pragma unroll
    for (int j = 0; j < 8; ++j) {
      unsigned short h = f2bf(fv[j]);
      ah[j] = (short)h;
      al[j] = (short)f2bf(fv[j] - bf2f(h));
    }
#pragma unroll
    for (int j = 0; j < 3; ++j) {
      int ncol = (nt0 + j) * 16 + c;
      bf16x8 bh = *reinterpret_cast<const bf16x8*>(&Wth[ncol * DIN + k0 + g * 8]);
      bf16x8 bl = *reinterpret_cast<const bf16x8*>(&Wtl[ncol * DIN + k0 + g * 8]);
      acc[j] = MFMA16(ah, bh, acc[j]);
      acc[j] = MFMA16(ah, bl, acc[j]);
      acc[j] = MFMA16(al, bh, acc[j]);
    }
  }
  // C layout: col=lane&15, row=(lane>>4)*4+r  (16-row tile)
#pragma unroll
  for (int j = 0; j < 3; ++j) {
    int nt = nt0 + j;
    if (nt < 8) {
#pragma unroll
      for (int r = 0; r < 4; ++r) {
        int Rrow = mbase + g * 4 + r;
        float v = acc[j][r];
        unsigned short h = f2bf(v);
        unsigned short lo = f2bf(v - bf2f(h));
        if (nt < 4) {
          Qh[Rrow * 64 + nt * 16 + c] = h;
          Ql[Rrow * 64 + nt * 16 + c] = lo;
        } else {
          Kh[Rrow * 64 + (nt - 4) * 16 + c] = h;
          Kl[Rrow * 64 + (nt - 4) * 16 + c] = lo;
        }
      }
    } else {
      int np = nt * 16 + c - 128;
      int Rbase = mbase + g * 4;
      u32x2 pk;
      pk.x = cvtpk(acc[j][0], acc[j][1]);
      pk.y = cvtpk(acc[j][2], acc[j][3]);
      *reinterpret_cast<u32x2*>(&Vt[(size_t)np * SLEN + Rbase]) = pk;  // V^T [64][8192]
    }
  }
}

// ---------------- D: flash attention, swapped 32x32 structure ----------------
template <int NS>
__global__ __launch_bounds__(256, 4) void k_flash(const unsigned short* __restrict__ Qh,
                                                  const unsigned short* __restrict__ Ql,
                                                  const unsigned short* __restrict__ Kh,
                                                  const unsigned short* __restrict__ Kl,
                                                  const unsigned short* __restrict__ Vt,
                                                  unsigned short* __restrict__ pOn,
                                                  float* __restrict__ pML) {
  constexpr int KIT = 128 / NS;   // 64-key tiles per split
  __shared__ __align__(16) unsigned char smem[3 * 8192];
  const int tid = threadIdx.x;
  const int wave = tid >> 6, lane = tid & 63;
  const int q32 = lane & 31, hi = lane >> 5;
  const int qtile = blockIdx.x;   // 32 q-tiles of 256
  const int ks = blockIdx.y;
  unsigned char* KH = smem;
  unsigned char* KL = smem + 8192;
  unsigned char* VT = smem + 16384;

  // Q B-fragments: B[k=hi*8+j][col=q32], per (qs, kk): bf16x8 of own q-row
  int qrow[2];
  bf16x8 qfh[2][4], qfl[2][4];
#pragma unroll
  for (int qs = 0; qs < 2; ++qs) {
    qrow[qs] = qtile * 256 + wave * 64 + qs * 32 + q32;
#pragma unroll
    for (int kk = 0; kk < 4; ++kk) {
      qfh[qs][kk] = *reinterpret_cast<const bf16x8*>(&Qh[qrow[qs] * 64 + kk * 16 + hi * 8]);
      qfl[qs][kk] = *reinterpret_cast<const bf16x8*>(&Ql[qrow[qs] * 64 + kk * 16 + hi * 8]);
    }
  }
  bf16x8 ones8;
#pragma unroll
  for (int j = 0; j < 8; ++j) ones8[j] = (short)0x3F80;

  f32x16 o[2][2];
#pragma unroll
  for (int qs = 0; qs < 2; ++qs)
#pragma unroll
    for (int db = 0; db < 2; ++db)
#pragma unroll
      for (int r = 0; r < 16; ++r) o[qs][db][r] = 0.f;
  float m_run[2] = {-1e30f, -1e30f};
  float l_run[2] = {0.f, 0.f};

  u32x4 st[6];
  auto LOADTILE = [&](int it) {
    const int kb = ks * (SLEN / NS) + it * 64;
#pragma unroll
    for (int u = 0; u < 6; ++u) {
      int unit = tid + u * 256;
      int idx = unit & 511, row = idx >> 3, seg = idx & 7;
      if (u < 2)      st[u] = *reinterpret_cast<const u32x4*>(&Kh[(kb + row) * 64 + seg * 8]);
      else if (u < 4) st[u] = *reinterpret_cast<const u32x4*>(&Kl[(kb + row) * 64 + seg * 8]);
      else            st[u] = *reinterpret_cast<const u32x4*>(&Vt[(size_t)row * SLEN + kb + seg * 8]);
    }
  };

  LOADTILE(0);
  for (int it = 0; it < KIT; ++it) {
    __syncthreads();
#pragma unroll
    for (int u = 0; u < 6; ++u) {
      int unit = tid + u * 256;
      int arr = unit >> 9, idx = unit & 511, row = idx >> 3, seg = idx & 7;
      *reinterpret_cast<u32x4*>(&smem[arr * 8192 + SW(row, seg * 16)]) = st[u];
    }
    __syncthreads();
    if (it + 1 < KIT) LOADTILE(it + 1);

#pragma unroll
    for (int s = 0; s < 2; ++s) {          // two 32-key subtiles
      bf16x8 kfh[4], kfl[4], vf[2][2];
#pragma unroll
      for (int kk = 0; kk < 4; ++kk) {
        kfh[kk] = *reinterpret_cast<const bf16x8*>(&KH[SW(32 * s + q32, 32 * kk + 16 * hi)]);
        kfl[kk] = *reinterpret_cast<const bf16x8*>(&KL[SW(32 * s + q32, 32 * kk + 16 * hi)]);
      }
#pragma unroll
      for (int db = 0; db < 2; ++db)
#pragma unroll
        for (int ch = 0; ch < 2; ++ch)
          vf[db][ch] = *reinterpret_cast<const bf16x8*>(&VT[SW(32 * db + q32, 64 * s + 32 * ch + 16 * hi)]);

#pragma unroll
      for (int qs = 0; qs < 2; ++qs) {
        // S^T = K·Q^T: D[k=crow(r,hi)][q=q32]
        f32x16 S;
#pragma unroll
        for (int r = 0; r < 16; ++r) S[r] = 0.f;
        __builtin_amdgcn_s_setprio(1);
#pragma unroll
        for (int kk = 0; kk < 4; ++kk) {
          S = MFMA32(kfh[kk], qfh[qs][kk], S);
          S = MFMA32(kfh[kk], qfl[qs][kk], S);
          S = MFMA32(kfl[kk], qfh[qs][kk], S);
        }
        __builtin_amdgcn_s_setprio(0);

        // lane-local row max (own 16 k) + cross-half combine
        float pm = S[0];
#pragma unroll
        for (int r = 1; r < 16; ++r) pm = fmaxf(pm, S[r]);
        pm = fmaxf(pm, __shfl_xor(pm, 32));
        if (!__all(pm - m_run[qs] <= 8.0f)) {   // defer-max (T13)
          float mnew = fmaxf(m_run[qs], pm);
          float alpha = exp2f(m_run[qs] - mnew);
#pragma unroll
          for (int db = 0; db < 2; ++db)
#pragma unroll
            for (int r = 0; r < 16; ++r) o[qs][db][r] *= alpha;
          l_run[qs] *= alpha;
          m_run[qs] = mnew;
        }
        float p[16];
#pragma unroll
        for (int r = 0; r < 16; ++r) p[r] = exp2f(S[r] - m_run[qs]);
        unsigned int W[8];
#pragma unroll
        for (int i = 0; i < 8; ++i) W[i] = cvtpk(p[2 * i], p[2 * i + 1]);
        // redistribute k-halves across lane halves -> PV B-fragments (T12)
        asm volatile("v_permlane32_swap_b32 %0, %1" : "+v"(W[0]), "+v"(W[2]));
        asm volatile("v_permlane32_swap_b32 %0, %1" : "+v"(W[1]), "+v"(W[3]));
        asm volatile("v_permlane32_swap_b32 %0, %1" : "+v"(W[4]), "+v"(W[6]));
        asm volatile("v_permlane32_swap_b32 %0, %1" : "+v"(W[5]), "+v"(W[7]));
        u32x4 pw0 = {W[0], W[1], W[2], W[3]};
        u32x4 pw1 = {W[4], W[5], W[6], W[7]};
        bf16x8 pb0 = *reinterpret_cast<bf16x8*>(&pw0);
        bf16x8 pb1 = *reinterpret_cast<bf16x8*>(&pw1);

        __builtin_amdgcn_s_setprio(1);
        f32x16 rs;
#pragma unroll
        for (int r = 0; r < 16; ++r) rs[r] = 0.f;
        rs = MFMA32(ones8, pb0, rs);            // rowsum[q] in every row
        rs = MFMA32(ones8, pb1, rs);
        // O^T[d][q] += V^T·P^T
        o[qs][0] = MFMA32(vf[0][0], pb0, o[qs][0]);
        o[qs][0] = MFMA32(vf[0][1], pb1, o[qs][0]);
        o[qs][1] = MFMA32(vf[1][0], pb0, o[qs][1]);
        o[qs][1] = MFMA32(vf[1][1], pb1, o[qs][1]);
        __builtin_amdgcn_s_setprio(0);
        l_run[qs] += rs[0];
      }
    }
  }

  // epilogue: normalized bf16 partials + (m,l)
#pragma unroll
  for (int qs = 0; qs < 2; ++qs) {
    float inv = 1.0f / l_run[qs];
#pragma unroll
    for (int db = 0; db < 2; ++db)
#pragma unroll
      for (int i = 0; i < 8; ++i) {
        unsigned int w = cvtpk(o[qs][db][2 * i] * inv, o[qs][db][2 * i + 1] * inv);
        int d = 2 * (i & 1) + 8 * (i >> 1) + 4 * hi + 32 * db;
        *reinterpret_cast<unsigned int*>(&pOn[((size_t)ks * SLEN + qrow[qs]) * 64 + d]) = w;
      }
    if (hi == 0) {
      pML[((size_t)ks * SLEN + qrow[qs]) * 2 + 0] = m_run[qs];
      pML[((size_t)ks * SLEN + qrow[qs]) * 2 + 1] = l_run[qs];
    }
  }
}

// ---------------- E: merge K-split partials (u32-pair vectorized) ----------------
template <int NS>
__global__ __launch_bounds__(256) void k_merge(const unsigned short* __restrict__ pOn,
                                               const float* __restrict__ pML,
                                               float* __restrict__ out) {
  int idx = blockIdx.x * 256 + threadIdx.x;  // 262144 u32-pairs
  int row = idx >> 5, dp = idx & 31;
  float ms[NS], ls[NS];
  float M = -1e30f;
#pragma unroll
  for (int s = 0; s < NS; ++s) {
    ms[s] = pML[((size_t)s * SLEN + row) * 2 + 0];
    ls[s] = pML[((size_t)s * SLEN + row) * 2 + 1];
    M = fmaxf(M, ms[s]);
  }
  float Wsum = 0.f, O0 = 0.f, O1 = 0.f;
  const unsigned int* pOn32 = reinterpret_cast<const unsigned int*>(pOn);
#pragma unroll
  for (int s = 0; s < NS; ++s) {
    float w = ls[s] * exp2f(ms[s] - M);
    unsigned int v = pOn32[((size_t)s * SLEN + row) * 32 + dp];
    O0 += w * bf2f((unsigned short)(v & 0xFFFF));
    O1 += w * bf2f((unsigned short)(v >> 16));
    Wsum += w;
  }
  float inv = 1.0f / Wsum;
  float2 res = {O0 * inv, O1 * inv};
  *reinterpret_cast<float2*>(&out[(size_t)row * 64 + dp * 2]) = res;
}

extern "C" void kernel_launch(void* const* d_in, const int* in_sizes, int n_in,
                              void* d_out, int out_size, void* d_ws, size_t ws_size,
                              hipStream_t stream) {
  const float* x  = (const float*)d_in[0];
  const float* Wq = (const float*)d_in[1];
  const float* Wk = (const float*)d_in[2];
  const float* Wv = (const float*)d_in[3];
  float* out = (float*)d_out;

  char* w = (char*)d_ws;
  const size_t QB = (size_t)SLEN * 64 * 2;       // 1,048,576 per buffer
  unsigned short* Qh = (unsigned short*)w;
  unsigned short* Ql = Qh + SLEN * 64;
  unsigned short* Kh = Ql + SLEN * 64;
  unsigned short* Kl = Kh + SLEN * 64;
  unsigned short* Vt = Kl + SLEN * 64;
  char* tail = w + 5 * QB;                       // 5,242,880
  // W lives in [tail, tail+393216): dead once k_qkv finishes; pML overlays it later
  unsigned short* Wth = (unsigned short*)tail;
  unsigned short* Wtl = Wth + 192 * DIN;

  k_splitw<<<dim3(384), dim3(256), 0, stream>>>(Wq, Wk, Wv, Wth, Wtl);
  k_qkv<<<dim3(512), dim3(256), 0, stream>>>(x, Wth, Wtl, Qh, Ql, Kh, Kl, Vt);

  const size_t need32 = 5 * QB + 32 * (size_t)SLEN * 8 + 32 * (size_t)SLEN * 64 * 2;
  const size_t need16 = 5 * QB + 16 * (size_t)SLEN * 8 + 16 * (size_t)SLEN * 64 * 2;
  if (ws_size >= need32) {
    float* pML = (float*)tail;                                   // 32*8192*2 f32 = 2 MB
    unsigned short* pOn = (unsigned short*)(tail + 32 * (size_t)SLEN * 8);
    k_flash<32><<<dim3(32, 32), dim3(256), 0, stream>>>(Qh, Ql, Kh, Kl, Vt, pOn, pML);
    k_merge<32><<<dim3(1024), dim3(256), 0, stream>>>(pOn, pML, out);
  } else if (ws_size >= need16) {
    float* pML = (float*)tail;                                   // 16*8192*2 f32 = 1 MB
    unsigned short* pOn = (unsigned short*)(tail + 16 * (size_t)SLEN * 8);
    k_flash<16><<<dim3(32, 16), dim3(256), 0, stream>>>(Qh, Ql, Kh, Kl, Vt, pOn, pML);
    k_merge<16><<<dim3(1024), dim3(256), 0, stream>>>(pOn, pML, out);
  } else {
    float* pML = (float*)tail;                                   // 8*8192*2 f32 = 0.5 MB
    unsigned short* pOn = (unsigned short*)(tail + 8 * (size_t)SLEN * 8);
    k_flash<8><<<dim3(32, 8), dim3(256), 0, stream>>>(Qh, Ql, Kh, Kl, Vt, pOn, pML);
    k_merge<8><<<dim3(1024), dim3(256), 0, stream>>>(pOn, pML, out);
  }
}

// Round 7
// 128.322 us; speedup vs baseline: 2.5014x; 2.5014x over previous
//
#include <hip/hip_runtime.h>

#define SLEN 8192
#define DIN  512

typedef short bf16x8 __attribute__((ext_vector_type(8)));
typedef float f32x4  __attribute__((ext_vector_type(4)));
typedef float f32x16 __attribute__((ext_vector_type(16)));
typedef unsigned int u32x4 __attribute__((ext_vector_type(4)));
typedef unsigned int u32x2 __attribute__((ext_vector_type(2)));

__device__ __forceinline__ unsigned short f2bf(float f) {
  unsigned int u = __float_as_uint(f);
  u += 0x7FFFu + ((u >> 16) & 1u);           // RNE
  return (unsigned short)(u >> 16);
}
__device__ __forceinline__ float bf2f(unsigned short h) {
  return __uint_as_float(((unsigned int)h) << 16);
}
__device__ __forceinline__ unsigned int cvtpk(float lo, float hi) {
  unsigned int r;
  asm volatile("v_cvt_pk_bf16_f32 %0, %1, %2" : "=v"(r) : "v"(lo), "v"(hi));
  return r;
}

#define MFMA16(a, b, c) __builtin_amdgcn_mfma_f32_16x16x32_bf16((a), (b), (c), 0, 0, 0)
#define MFMA32(a, b, c) __builtin_amdgcn_mfma_f32_32x32x16_bf16((a), (b), (c), 0, 0, 0)

// XOR swizzle for [row][128B] LDS tiles
__device__ __forceinline__ int SW(int row, int off) {
  return row * 128 + (off ^ ((row & 7) << 4));
}

// ------- B: split + transpose W -> Wt[n][k], n: 0-63 Q(scaled), 64-127 K, 128-191 V -------
__global__ __launch_bounds__(256) void k_splitw(const float* __restrict__ Wq,
                                                const float* __restrict__ Wk,
                                                const float* __restrict__ Wv,
                                                unsigned short* __restrict__ Wth,
                                                unsigned short* __restrict__ Wtl) {
  int idx = blockIdx.x * 256 + threadIdx.x;  // n*512 + k, 98304 total
  int n = idx >> 9, k = idx & 511;
  float w;
  if (n < 64)       w = Wq[k * 64 + n] * 0.18033688011112042f;  // log2(e)/8 folded in
  else if (n < 128) w = Wk[k * 64 + (n - 64)];
  else              w = Wv[k * 64 + (n - 128)];
  unsigned short h = f2bf(w);
  Wth[idx] = h;
  Wtl[idx] = f2bf(w - bf2f(h));
}

// ---------------- C: QKV = x @ [Wq|Wk|Wv], x read ONCE, 16-row m-tiles ----------------
__global__ __launch_bounds__(256) void k_qkv(const float* __restrict__ x,
                                             const unsigned short* __restrict__ Wth,
                                             const unsigned short* __restrict__ Wtl,
                                             unsigned short* __restrict__ Qh,
                                             unsigned short* __restrict__ Ql,
                                             unsigned short* __restrict__ Kh,
                                             unsigned short* __restrict__ Kl,
                                             unsigned short* __restrict__ Vt) {
  const int tid = threadIdx.x;
  const int wave = tid >> 6, lane = tid & 63;
  const int c = lane & 15, g = lane >> 4;
  const int mbase = blockIdx.x * 16;              // 512 m-tiles of 16 rows
  const int nt0 = wave * 3;                       // each wave: 3 of 12 n-tiles

  const int rowA = mbase + c;                     // all waves share rows (L1 broadcast)
  f32x4 acc[3];
  for (int j = 0; j < 3; ++j) acc[j] = (f32x4){0.f, 0.f, 0.f, 0.f};

  for (int k0 = 0; k0 < DIN; k0 += 32) {
    const float* xp = x + (size_t)rowA * DIN + k0 + g * 8;
    float4 f0 = *reinterpret_cast<const float4*>(xp);
    float4 f1 = *reinterpret_cast<const float4*>(xp + 4);
    float fv[8] = {f0.x, f0.y, f0.z, f0.w, f1.x, f1.y, f1.z, f1.w};
    bf16x8 ah, al;
#pragma unroll
    for (int j = 0; j < 8; ++j) {
      unsigned short h = f2bf(fv[j]);
      ah[j] = (short)h;
      al[j] = (short)f2bf(fv[j] - bf2f(h));
    }
#pragma unroll
    for (int j = 0; j < 3; ++j) {
      int ncol = (nt0 + j) * 16 + c;
      bf16x8 bh = *reinterpret_cast<const bf16x8*>(&Wth[ncol * DIN + k0 + g * 8]);
      bf16x8 bl = *reinterpret_cast<const bf16x8*>(&Wtl[ncol * DIN + k0 + g * 8]);
      acc[j] = MFMA16(ah, bh, acc[j]);
      acc[j] = MFMA16(ah, bl, acc[j]);
      acc[j] = MFMA16(al, bh, acc[j]);
    }
  }
  // C layout: col=lane&15, row=(lane>>4)*4+r  (16-row tile)
#pragma unroll
  for (int j = 0; j < 3; ++j) {
    int nt = nt0 + j;
    if (nt < 8) {
#pragma unroll
      for (int r = 0; r < 4; ++r) {
        int Rrow = mbase + g * 4 + r;
        float v = acc[j][r];
        unsigned short h = f2bf(v);
        unsigned short lo = f2bf(v - bf2f(h));
        if (nt < 4) {
          Qh[Rrow * 64 + nt * 16 + c] = h;
          Ql[Rrow * 64 + nt * 16 + c] = lo;
        } else {
          Kh[Rrow * 64 + (nt - 4) * 16 + c] = h;
          Kl[Rrow * 64 + (nt - 4) * 16 + c] = lo;
        }
      }
    } else {
      int np = nt * 16 + c - 128;
      int Rbase = mbase + g * 4;
      u32x2 pk;
      pk.x = cvtpk(acc[j][0], acc[j][1]);
      pk.y = cvtpk(acc[j][2], acc[j][3]);
      *reinterpret_cast<u32x2*>(&Vt[(size_t)np * SLEN + Rbase]) = pk;  // V^T [64][8192]
    }
  }
}

// ---------------- D: flash attention, swapped 32x32, 32 q-rows per wave ----------------
template <int NS>
__global__ __launch_bounds__(256, 3) void k_flash(const unsigned short* __restrict__ Qh,
                                                  const unsigned short* __restrict__ Ql,
                                                  const unsigned short* __restrict__ Kh,
                                                  const unsigned short* __restrict__ Kl,
                                                  const unsigned short* __restrict__ Vt,
                                                  unsigned short* __restrict__ pOn,
                                                  float* __restrict__ pML) {
  constexpr int KIT = 128 / NS;   // 64-key tiles per split
  __shared__ __align__(16) unsigned char smem[3 * 8192];
  const int tid = threadIdx.x;
  const int wave = tid >> 6, lane = tid & 63;
  const int q32 = lane & 31, hi = lane >> 5;
  const int qtile = blockIdx.x;   // 64 q-tiles of 128
  const int ks = blockIdx.y;
  unsigned char* KH = smem;
  unsigned char* KL = smem + 8192;
  unsigned char* VT = smem + 16384;

  // Q B-fragments: B[k=hi*8+j][col=q32], bf16x8 of own q-row
  const int qrow = qtile * 128 + wave * 32 + q32;
  bf16x8 qfh[4], qfl[4];
#pragma unroll
  for (int kk = 0; kk < 4; ++kk) {
    qfh[kk] = *reinterpret_cast<const bf16x8*>(&Qh[qrow * 64 + kk * 16 + hi * 8]);
    qfl[kk] = *reinterpret_cast<const bf16x8*>(&Ql[qrow * 64 + kk * 16 + hi * 8]);
  }
  bf16x8 ones8;
#pragma unroll
  for (int j = 0; j < 8; ++j) ones8[j] = (short)0x3F80;

  f32x16 o[2];
#pragma unroll
  for (int db = 0; db < 2; ++db)
#pragma unroll
    for (int r = 0; r < 16; ++r) o[db][r] = 0.f;
  float m_run = -1e30f;
  float l_run = 0.f;

  u32x4 st[6];
  auto LOADTILE = [&](int it) {
    const int kb = ks * (SLEN / NS) + it * 64;
#pragma unroll
    for (int u = 0; u < 6; ++u) {
      int unit = tid + u * 256;
      int idx = unit & 511, row = idx >> 3, seg = idx & 7;
      if (u < 2)      st[u] = *reinterpret_cast<const u32x4*>(&Kh[(kb + row) * 64 + seg * 8]);
      else if (u < 4) st[u] = *reinterpret_cast<const u32x4*>(&Kl[(kb + row) * 64 + seg * 8]);
      else            st[u] = *reinterpret_cast<const u32x4*>(&Vt[(size_t)row * SLEN + kb + seg * 8]);
    }
  };

  LOADTILE(0);
  for (int it = 0; it < KIT; ++it) {
    __syncthreads();
#pragma unroll
    for (int u = 0; u < 6; ++u) {
      int unit = tid + u * 256;
      int arr = unit >> 9, idx = unit & 511, row = idx >> 3, seg = idx & 7;
      *reinterpret_cast<u32x4*>(&smem[arr * 8192 + SW(row, seg * 16)]) = st[u];
    }
    __syncthreads();
    if (it + 1 < KIT) LOADTILE(it + 1);   // loads fly during compute

#pragma unroll
    for (int s = 0; s < 2; ++s) {          // two 32-key subtiles
      bf16x8 kfh[4], kfl[4], vf[2][2];
#pragma unroll
      for (int kk = 0; kk < 4; ++kk) {
        kfh[kk] = *reinterpret_cast<const bf16x8*>(&KH[SW(32 * s + q32, 32 * kk + 16 * hi)]);
        kfl[kk] = *reinterpret_cast<const bf16x8*>(&KL[SW(32 * s + q32, 32 * kk + 16 * hi)]);
      }
#pragma unroll
      for (int db = 0; db < 2; ++db)
#pragma unroll
        for (int ch = 0; ch < 2; ++ch)
          vf[db][ch] = *reinterpret_cast<const bf16x8*>(&VT[SW(32 * db + q32, 64 * s + 32 * ch + 16 * hi)]);

      // S^T = K·Q^T: D[k=crow(r,hi)][q=q32]
      f32x16 S;
#pragma unroll
      for (int r = 0; r < 16; ++r) S[r] = 0.f;
      __builtin_amdgcn_s_setprio(1);
#pragma unroll
      for (int kk = 0; kk < 4; ++kk) {
        S = MFMA32(kfh[kk], qfh[kk], S);
        S = MFMA32(kfh[kk], qfl[kk], S);
        S = MFMA32(kfl[kk], qfh[kk], S);
      }
      __builtin_amdgcn_s_setprio(0);

      // lane-local row max (own 16 k) + cross-half combine
      float pm = S[0];
#pragma unroll
      for (int r = 1; r < 16; ++r) pm = fmaxf(pm, S[r]);
      pm = fmaxf(pm, __shfl_xor(pm, 32));
      if (!__all(pm - m_run <= 8.0f)) {   // defer-max (T13)
        float mnew = fmaxf(m_run, pm);
        float alpha = exp2f(m_run - mnew);
#pragma unroll
        for (int db = 0; db < 2; ++db)
#pragma unroll
          for (int r = 0; r < 16; ++r) o[db][r] *= alpha;
        l_run *= alpha;
        m_run = mnew;
      }
      float p[16];
#pragma unroll
      for (int r = 0; r < 16; ++r) p[r] = exp2f(S[r] - m_run);
      unsigned int W[8];
#pragma unroll
      for (int i = 0; i < 8; ++i) W[i] = cvtpk(p[2 * i], p[2 * i + 1]);
      // redistribute k-halves across lane halves -> PV B-fragments (T12)
      asm volatile("v_permlane32_swap_b32 %0, %1" : "+v"(W[0]), "+v"(W[2]));
      asm volatile("v_permlane32_swap_b32 %0, %1" : "+v"(W[1]), "+v"(W[3]));
      asm volatile("v_permlane32_swap_b32 %0, %1" : "+v"(W[4]), "+v"(W[6]));
      asm volatile("v_permlane32_swap_b32 %0, %1" : "+v"(W[5]), "+v"(W[7]));
      u32x4 pw0 = {W[0], W[1], W[2], W[3]};
      u32x4 pw1 = {W[4], W[5], W[6], W[7]};
      bf16x8 pb0 = *reinterpret_cast<bf16x8*>(&pw0);
      bf16x8 pb1 = *reinterpret_cast<bf16x8*>(&pw1);

      __builtin_amdgcn_s_setprio(1);
      f32x16 rs;
#pragma unroll
      for (int r = 0; r < 16; ++r) rs[r] = 0.f;
      rs = MFMA32(ones8, pb0, rs);            // rowsum[q] in every row
      rs = MFMA32(ones8, pb1, rs);
      // O^T[d][q] += V^T·P^T
      o[0] = MFMA32(vf[0][0], pb0, o[0]);
      o[0] = MFMA32(vf[0][1], pb1, o[0]);
      o[1] = MFMA32(vf[1][0], pb0, o[1]);
      o[1] = MFMA32(vf[1][1], pb1, o[1]);
      __builtin_amdgcn_s_setprio(0);
      l_run += rs[0];
    }
  }

  // epilogue: normalized bf16 partials + (m,l)
  float inv = 1.0f / l_run;
#pragma unroll
  for (int db = 0; db < 2; ++db)
#pragma unroll
    for (int i = 0; i < 8; ++i) {
      unsigned int w = cvtpk(o[db][2 * i] * inv, o[db][2 * i + 1] * inv);
      int d = 2 * (i & 1) + 8 * (i >> 1) + 4 * hi + 32 * db;
      *reinterpret_cast<unsigned int*>(&pOn[((size_t)ks * SLEN + qrow) * 64 + d]) = w;
    }
  if (hi == 0) {
    pML[((size_t)ks * SLEN + qrow) * 2 + 0] = m_run;
    pML[((size_t)ks * SLEN + qrow) * 2 + 1] = l_run;
  }
}

// ---------------- E: merge K-split partials (u32-pair vectorized) ----------------
template <int NS>
__global__ __launch_bounds__(256) void k_merge(const unsigned short* __restrict__ pOn,
                                               const float* __restrict__ pML,
                                               float* __restrict__ out) {
  int idx = blockIdx.x * 256 + threadIdx.x;  // 262144 u32-pairs
  int row = idx >> 5, dp = idx & 31;
  float ms[NS], ls[NS];
  float M = -1e30f;
#pragma unroll
  for (int s = 0; s < NS; ++s) {
    ms[s] = pML[((size_t)s * SLEN + row) * 2 + 0];
    ls[s] = pML[((size_t)s * SLEN + row) * 2 + 1];
    M = fmaxf(M, ms[s]);
  }
  float Wsum = 0.f, O0 = 0.f, O1 = 0.f;
  const unsigned int* pOn32 = reinterpret_cast<const unsigned int*>(pOn);
#pragma unroll
  for (int s = 0; s < NS; ++s) {
    float w = ls[s] * exp2f(ms[s] - M);
    unsigned int v = pOn32[((size_t)s * SLEN + row) * 32 + dp];
    O0 += w * bf2f((unsigned short)(v & 0xFFFF));
    O1 += w * bf2f((unsigned short)(v >> 16));
    Wsum += w;
  }
  float inv = 1.0f / Wsum;
  float2 res = {O0 * inv, O1 * inv};
  *reinterpret_cast<float2*>(&out[(size_t)row * 64 + dp * 2]) = res;
}

extern "C" void kernel_launch(void* const* d_in, const int* in_sizes, int n_in,
                              void* d_out, int out_size, void* d_ws, size_t ws_size,
                              hipStream_t stream) {
  const float* x  = (const float*)d_in[0];
  const float* Wq = (const float*)d_in[1];
  const float* Wk = (const float*)d_in[2];
  const float* Wv = (const float*)d_in[3];
  float* out = (float*)d_out;

  char* w = (char*)d_ws;
  const size_t QB = (size_t)SLEN * 64 * 2;       // 1,048,576 per buffer
  unsigned short* Qh = (unsigned short*)w;
  unsigned short* Ql = Qh + SLEN * 64;
  unsigned short* Kh = Ql + SLEN * 64;
  unsigned short* Kl = Kh + SLEN * 64;
  unsigned short* Vt = Kl + SLEN * 64;
  char* tail = w + 5 * QB;                       // 5,242,880
  // W lives in [tail, tail+393216): dead once k_qkv finishes; pML overlays it later
  unsigned short* Wth = (unsigned short*)tail;
  unsigned short* Wtl = Wth + 192 * DIN;

  k_splitw<<<dim3(384), dim3(256), 0, stream>>>(Wq, Wk, Wv, Wth, Wtl);
  k_qkv<<<dim3(512), dim3(256), 0, stream>>>(x, Wth, Wtl, Qh, Ql, Kh, Kl, Vt);

  const size_t need32 = 5 * QB + 32 * (size_t)SLEN * 8 + 32 * (size_t)SLEN * 64 * 2;
  const size_t need16 = 5 * QB + 16 * (size_t)SLEN * 8 + 16 * (size_t)SLEN * 64 * 2;
  if (ws_size >= need32) {
    float* pML = (float*)tail;                                   // 32*8192*2 f32 = 2 MB
    unsigned short* pOn = (unsigned short*)(tail + 32 * (size_t)SLEN * 8);
    k_flash<32><<<dim3(64, 32), dim3(256), 0, stream>>>(Qh, Ql, Kh, Kl, Vt, pOn, pML);
    k_merge<32><<<dim3(1024), dim3(256), 0, stream>>>(pOn, pML, out);
  } else if (ws_size >= need16) {
    float* pML = (float*)tail;                                   // 16*8192*2 f32 = 1 MB
    unsigned short* pOn = (unsigned short*)(tail + 16 * (size_t)SLEN * 8);
    k_flash<16><<<dim3(64, 16), dim3(256), 0, stream>>>(Qh, Ql, Kh, Kl, Vt, pOn, pML);
    k_merge<16><<<dim3(1024), dim3(256), 0, stream>>>(pOn, pML, out);
  } else {
    float* pML = (float*)tail;                                   // 8*8192*2 f32 = 0.5 MB
    unsigned short* pOn = (unsigned short*)(tail + 8 * (size_t)SLEN * 8);
    k_flash<8><<<dim3(64, 8), dim3(256), 0, stream>>>(Qh, Ql, Kh, Kl, Vt, pOn, pML);
    k_merge<8><<<dim3(1024), dim3(256), 0, stream>>>(pOn, pML, out);
  }
}

// Round 8
// 112.323 us; speedup vs baseline: 2.8577x; 1.1424x over previous
//
#include <hip/hip_runtime.h>

#define SLEN 8192
#define DIN  512

typedef short bf16x8 __attribute__((ext_vector_type(8)));
typedef float f32x4  __attribute__((ext_vector_type(4)));
typedef float f32x16 __attribute__((ext_vector_type(16)));
typedef unsigned int u32x4 __attribute__((ext_vector_type(4)));
typedef unsigned int u32x2 __attribute__((ext_vector_type(2)));

__device__ __forceinline__ unsigned short f2bf(float f) {
  unsigned int u = __float_as_uint(f);
  u += 0x7FFFu + ((u >> 16) & 1u);           // RNE
  return (unsigned short)(u >> 16);
}
__device__ __forceinline__ float bf2f(unsigned short h) {
  return __uint_as_float(((unsigned int)h) << 16);
}
__device__ __forceinline__ unsigned int cvtpk(float lo, float hi) {
  unsigned int r;
  asm volatile("v_cvt_pk_bf16_f32 %0, %1, %2" : "=v"(r) : "v"(lo), "v"(hi));
  return r;
}

#define MFMA16(a, b, c) __builtin_amdgcn_mfma_f32_16x16x32_bf16((a), (b), (c), 0, 0, 0)
#define MFMA32(a, b, c) __builtin_amdgcn_mfma_f32_32x32x16_bf16((a), (b), (c), 0, 0, 0)

// XOR swizzle for [row][128B] LDS tiles
__device__ __forceinline__ int SW(int row, int off) {
  return row * 128 + (off ^ ((row & 7) << 4));
}

// ------- B: split + transpose W -> Wt[n][k], n: 0-63 Q(scaled), 64-127 K, 128-191 V -------
__global__ __launch_bounds__(256) void k_splitw(const float* __restrict__ Wq,
                                                const float* __restrict__ Wk,
                                                const float* __restrict__ Wv,
                                                unsigned short* __restrict__ Wth,
                                                unsigned short* __restrict__ Wtl) {
  int idx = blockIdx.x * 256 + threadIdx.x;  // n*512 + k, 98304 total
  int n = idx >> 9, k = idx & 511;
  float w;
  if (n < 64)       w = Wq[k * 64 + n] * 0.18033688011112042f;  // log2(e)/8 folded in
  else if (n < 128) w = Wk[k * 64 + (n - 64)];
  else              w = Wv[k * 64 + (n - 128)];
  unsigned short h = f2bf(w);
  Wth[idx] = h;
  Wtl[idx] = f2bf(w - bf2f(h));
}

// ---------------- C: QKV = x @ [Wq|Wk|Wv], x read ONCE, 16-row m-tiles ----------------
__global__ __launch_bounds__(256) void k_qkv(const float* __restrict__ x,
                                             const unsigned short* __restrict__ Wth,
                                             const unsigned short* __restrict__ Wtl,
                                             unsigned short* __restrict__ Qh,
                                             unsigned short* __restrict__ Ql,
                                             unsigned short* __restrict__ Kh,
                                             unsigned short* __restrict__ Kl,
                                             unsigned short* __restrict__ Vt) {
  const int tid = threadIdx.x;
  const int wave = tid >> 6, lane = tid & 63;
  const int c = lane & 15, g = lane >> 4;
  const int mbase = blockIdx.x * 16;              // 512 m-tiles of 16 rows
  const int nt0 = wave * 3;                       // each wave: 3 of 12 n-tiles

  const int rowA = mbase + c;                     // all waves share rows (L1 broadcast)
  f32x4 acc[3];
  for (int j = 0; j < 3; ++j) acc[j] = (f32x4){0.f, 0.f, 0.f, 0.f};

  for (int k0 = 0; k0 < DIN; k0 += 32) {
    const float* xp = x + (size_t)rowA * DIN + k0 + g * 8;
    float4 f0 = *reinterpret_cast<const float4*>(xp);
    float4 f1 = *reinterpret_cast<const float4*>(xp + 4);
    float fv[8] = {f0.x, f0.y, f0.z, f0.w, f1.x, f1.y, f1.z, f1.w};
    bf16x8 ah, al;
#pragma unroll
    for (int j = 0; j < 8; ++j) {
      unsigned short h = f2bf(fv[j]);
      ah[j] = (short)h;
      al[j] = (short)f2bf(fv[j] - bf2f(h));
    }
#pragma unroll
    for (int j = 0; j < 3; ++j) {
      int ncol = (nt0 + j) * 16 + c;
      bf16x8 bh = *reinterpret_cast<const bf16x8*>(&Wth[ncol * DIN + k0 + g * 8]);
      bf16x8 bl = *reinterpret_cast<const bf16x8*>(&Wtl[ncol * DIN + k0 + g * 8]);
      acc[j] = MFMA16(ah, bh, acc[j]);
      acc[j] = MFMA16(ah, bl, acc[j]);
      acc[j] = MFMA16(al, bh, acc[j]);
    }
  }
  // C layout: col=lane&15, row=(lane>>4)*4+r  (16-row tile)
#pragma unroll
  for (int j = 0; j < 3; ++j) {
    int nt = nt0 + j;
    if (nt < 8) {
#pragma unroll
      for (int r = 0; r < 4; ++r) {
        int Rrow = mbase + g * 4 + r;
        float v = acc[j][r];
        unsigned short h = f2bf(v);
        unsigned short lo = f2bf(v - bf2f(h));
        if (nt < 4) {
          Qh[Rrow * 64 + nt * 16 + c] = h;
          Ql[Rrow * 64 + nt * 16 + c] = lo;
        } else {
          Kh[Rrow * 64 + (nt - 4) * 16 + c] = h;
          Kl[Rrow * 64 + (nt - 4) * 16 + c] = lo;
        }
      }
    } else {
      int np = nt * 16 + c - 128;
      int Rbase = mbase + g * 4;
      u32x2 pk;
      pk.x = cvtpk(acc[j][0], acc[j][1]);
      pk.y = cvtpk(acc[j][2], acc[j][3]);
      *reinterpret_cast<u32x2*>(&Vt[(size_t)np * SLEN + Rbase]) = pk;  // V^T [64][8192]
    }
  }
}

// ---------------- D: flash attention, swapped 32x32, 64 q-rows/wave ----------------
template <int NS>
__global__ __launch_bounds__(256, 2) void k_flash(const unsigned short* __restrict__ Qh,
                                                  const unsigned short* __restrict__ Ql,
                                                  const unsigned short* __restrict__ Kh,
                                                  const unsigned short* __restrict__ Kl,
                                                  const unsigned short* __restrict__ Vt,
                                                  unsigned short* __restrict__ pOn,
                                                  float* __restrict__ pML) {
  constexpr int KIT = 128 / NS;   // 64-key tiles per split
  __shared__ __align__(16) unsigned char smem[3 * 8192];
  const int tid = threadIdx.x;
  const int wave = tid >> 6, lane = tid & 63;
  const int q32 = lane & 31, hi = lane >> 5;
  const int qtile = blockIdx.x;   // 32 q-tiles of 256
  const int ks = blockIdx.y;
  unsigned char* KH = smem;
  unsigned char* KL = smem + 8192;
  unsigned char* VT = smem + 16384;

  // Q B-fragments: B[k=hi*8+j][col=q32], per (qs, kk): bf16x8 of own q-row
  int qrow[2];
  bf16x8 qfh[2][4], qfl[2][4];
#pragma unroll
  for (int qs = 0; qs < 2; ++qs) {
    qrow[qs] = qtile * 256 + wave * 64 + qs * 32 + q32;
#pragma unroll
    for (int kk = 0; kk < 4; ++kk) {
      qfh[qs][kk] = *reinterpret_cast<const bf16x8*>(&Qh[qrow[qs] * 64 + kk * 16 + hi * 8]);
      qfl[qs][kk] = *reinterpret_cast<const bf16x8*>(&Ql[qrow[qs] * 64 + kk * 16 + hi * 8]);
    }
  }
  bf16x8 ones8;
#pragma unroll
  for (int j = 0; j < 8; ++j) ones8[j] = (short)0x3F80;

  f32x16 o[2][2];
#pragma unroll
  for (int qs = 0; qs < 2; ++qs)
#pragma unroll
    for (int db = 0; db < 2; ++db)
#pragma unroll
      for (int r = 0; r < 16; ++r) o[qs][db][r] = 0.f;
  float m_run[2] = {-1e30f, -1e30f};
  float l_run[2] = {0.f, 0.f};

  u32x4 st[6];
  auto LOADTILE = [&](int it) {
    const int kb = ks * (SLEN / NS) + it * 64;
#pragma unroll
    for (int u = 0; u < 6; ++u) {
      int unit = tid + u * 256;
      int idx = unit & 511, row = idx >> 3, seg = idx & 7;
      if (u < 2)      st[u] = *reinterpret_cast<const u32x4*>(&Kh[(kb + row) * 64 + seg * 8]);
      else if (u < 4) st[u] = *reinterpret_cast<const u32x4*>(&Kl[(kb + row) * 64 + seg * 8]);
      else            st[u] = *reinterpret_cast<const u32x4*>(&Vt[(size_t)row * SLEN + kb + seg * 8]);
    }
  };

  LOADTILE(0);
  for (int it = 0; it < KIT; ++it) {
    __syncthreads();
#pragma unroll
    for (int u = 0; u < 6; ++u) {
      int unit = tid + u * 256;
      int arr = unit >> 9, idx = unit & 511, row = idx >> 3, seg = idx & 7;
      *reinterpret_cast<u32x4*>(&smem[arr * 8192 + SW(row, seg * 16)]) = st[u];
    }
    __syncthreads();
    if (it + 1 < KIT) LOADTILE(it + 1);   // loads fly during compute

#pragma unroll
    for (int s = 0; s < 2; ++s) {          // two 32-key subtiles
      bf16x8 kfh[4], kfl[4], vf[2][2];
#pragma unroll
      for (int kk = 0; kk < 4; ++kk) {
        kfh[kk] = *reinterpret_cast<const bf16x8*>(&KH[SW(32 * s + q32, 32 * kk + 16 * hi)]);
        kfl[kk] = *reinterpret_cast<const bf16x8*>(&KL[SW(32 * s + q32, 32 * kk + 16 * hi)]);
      }
#pragma unroll
      for (int db = 0; db < 2; ++db)
#pragma unroll
        for (int ch = 0; ch < 2; ++ch)
          vf[db][ch] = *reinterpret_cast<const bf16x8*>(&VT[SW(32 * db + q32, 64 * s + 32 * ch + 16 * hi)]);

      // S^T = K·Q^T for BOTH qs, chains interleaved (dep distance 2)
      f32x16 S[2];
#pragma unroll
      for (int r = 0; r < 16; ++r) { S[0][r] = 0.f; S[1][r] = 0.f; }
      __builtin_amdgcn_s_setprio(1);
#pragma unroll
      for (int kk = 0; kk < 4; ++kk) {
        S[0] = MFMA32(kfh[kk], qfh[0][kk], S[0]);
        S[1] = MFMA32(kfh[kk], qfh[1][kk], S[1]);
        S[0] = MFMA32(kfh[kk], qfl[0][kk], S[0]);
        S[1] = MFMA32(kfh[kk], qfl[1][kk], S[1]);
        S[0] = MFMA32(kfl[kk], qfh[0][kk], S[0]);
        S[1] = MFMA32(kfl[kk], qfh[1][kk], S[1]);
      }
      __builtin_amdgcn_s_setprio(0);

#pragma unroll
      for (int qs = 0; qs < 2; ++qs) {
        // tree max over own 16 k-slots
        float a0 = fmaxf(S[qs][0], S[qs][1]),  a1 = fmaxf(S[qs][2], S[qs][3]);
        float a2 = fmaxf(S[qs][4], S[qs][5]),  a3 = fmaxf(S[qs][6], S[qs][7]);
        float a4 = fmaxf(S[qs][8], S[qs][9]),  a5 = fmaxf(S[qs][10], S[qs][11]);
        float a6 = fmaxf(S[qs][12], S[qs][13]), a7 = fmaxf(S[qs][14], S[qs][15]);
        float b0 = fmaxf(a0, a1), b1 = fmaxf(a2, a3), b2 = fmaxf(a4, a5), b3 = fmaxf(a6, a7);
        float pm = fmaxf(fmaxf(b0, b1), fmaxf(b2, b3));
        pm = fmaxf(pm, __shfl_xor(pm, 32));
        // branchless online rescale (rescale fires ~every tile at 32 rows/__all anyway)
        float mnew = fmaxf(m_run[qs], pm);
        float alpha = exp2f(m_run[qs] - mnew);
        m_run[qs] = mnew;
        l_run[qs] *= alpha;
#pragma unroll
        for (int db = 0; db < 2; ++db)
#pragma unroll
          for (int r = 0; r < 16; ++r) o[qs][db][r] *= alpha;

        float p[16];
#pragma unroll
        for (int r = 0; r < 16; ++r) p[r] = exp2f(S[qs][r] - mnew);
        unsigned int W[8];
#pragma unroll
        for (int i = 0; i < 8; ++i) W[i] = cvtpk(p[2 * i], p[2 * i + 1]);
        // redistribute k-halves across lane halves -> PV B-fragments (T12)
        asm volatile("v_permlane32_swap_b32 %0, %1" : "+v"(W[0]), "+v"(W[2]));
        asm volatile("v_permlane32_swap_b32 %0, %1" : "+v"(W[1]), "+v"(W[3]));
        asm volatile("v_permlane32_swap_b32 %0, %1" : "+v"(W[4]), "+v"(W[6]));
        asm volatile("v_permlane32_swap_b32 %0, %1" : "+v"(W[5]), "+v"(W[7]));
        u32x4 pw0 = {W[0], W[1], W[2], W[3]};
        u32x4 pw1 = {W[4], W[5], W[6], W[7]};
        bf16x8 pb0 = *reinterpret_cast<bf16x8*>(&pw0);
        bf16x8 pb1 = *reinterpret_cast<bf16x8*>(&pw1);

        __builtin_amdgcn_s_setprio(1);
        f32x16 rs;
#pragma unroll
        for (int r = 0; r < 16; ++r) rs[r] = 0.f;
        rs = MFMA32(ones8, pb0, rs);            // rowsum[q] in every row
        rs = MFMA32(ones8, pb1, rs);
        // O^T[d][q] += V^T·P^T
        o[qs][0] = MFMA32(vf[0][0], pb0, o[qs][0]);
        o[qs][0] = MFMA32(vf[0][1], pb1, o[qs][0]);
        o[qs][1] = MFMA32(vf[1][0], pb0, o[qs][1]);
        o[qs][1] = MFMA32(vf[1][1], pb1, o[qs][1]);
        __builtin_amdgcn_s_setprio(0);
        l_run[qs] += rs[0];
      }
    }
  }

  // epilogue: normalized bf16 partials + (m,l)
#pragma unroll
  for (int qs = 0; qs < 2; ++qs) {
    float inv = 1.0f / l_run[qs];
#pragma unroll
    for (int db = 0; db < 2; ++db)
#pragma unroll
      for (int i = 0; i < 8; ++i) {
        unsigned int w = cvtpk(o[qs][db][2 * i] * inv, o[qs][db][2 * i + 1] * inv);
        int d = 2 * (i & 1) + 8 * (i >> 1) + 4 * hi + 32 * db;
        *reinterpret_cast<unsigned int*>(&pOn[((size_t)ks * SLEN + qrow[qs]) * 64 + d]) = w;
      }
    if (hi == 0) {
      pML[((size_t)ks * SLEN + qrow[qs]) * 2 + 0] = m_run[qs];
      pML[((size_t)ks * SLEN + qrow[qs]) * 2 + 1] = l_run[qs];
    }
  }
}

// ---------------- E: merge K-split partials (u32-pair vectorized) ----------------
template <int NS>
__global__ __launch_bounds__(256) void k_merge(const unsigned short* __restrict__ pOn,
                                               const float* __restrict__ pML,
                                               float* __restrict__ out) {
  int idx = blockIdx.x * 256 + threadIdx.x;  // 262144 u32-pairs
  int row = idx >> 5, dp = idx & 31;
  float ms[NS], ls[NS];
  float M = -1e30f;
#pragma unroll
  for (int s = 0; s < NS; ++s) {
    ms[s] = pML[((size_t)s * SLEN + row) * 2 + 0];
    ls[s] = pML[((size_t)s * SLEN + row) * 2 + 1];
    M = fmaxf(M, ms[s]);
  }
  float Wsum = 0.f, O0 = 0.f, O1 = 0.f;
  const unsigned int* pOn32 = reinterpret_cast<const unsigned int*>(pOn);
#pragma unroll
  for (int s = 0; s < NS; ++s) {
    float w = ls[s] * exp2f(ms[s] - M);
    unsigned int v = pOn32[((size_t)s * SLEN + row) * 32 + dp];
    O0 += w * bf2f((unsigned short)(v & 0xFFFF));
    O1 += w * bf2f((unsigned short)(v >> 16));
    Wsum += w;
  }
  float inv = 1.0f / Wsum;
  float2 res = {O0 * inv, O1 * inv};
  *reinterpret_cast<float2*>(&out[(size_t)row * 64 + dp * 2]) = res;
}

extern "C" void kernel_launch(void* const* d_in, const int* in_sizes, int n_in,
                              void* d_out, int out_size, void* d_ws, size_t ws_size,
                              hipStream_t stream) {
  const float* x  = (const float*)d_in[0];
  const float* Wq = (const float*)d_in[1];
  const float* Wk = (const float*)d_in[2];
  const float* Wv = (const float*)d_in[3];
  float* out = (float*)d_out;

  char* w = (char*)d_ws;
  const size_t QB = (size_t)SLEN * 64 * 2;       // 1,048,576 per buffer
  unsigned short* Qh = (unsigned short*)w;
  unsigned short* Ql = Qh + SLEN * 64;
  unsigned short* Kh = Ql + SLEN * 64;
  unsigned short* Kl = Kh + SLEN * 64;
  unsigned short* Vt = Kl + SLEN * 64;
  char* tail = w + 5 * QB;                       // 5,242,880
  // W lives in [tail, tail+393216): dead once k_qkv finishes; pML overlays it later
  unsigned short* Wth = (unsigned short*)tail;
  unsigned short* Wtl = Wth + 192 * DIN;

  k_splitw<<<dim3(384), dim3(256), 0, stream>>>(Wq, Wk, Wv, Wth, Wtl);
  k_qkv<<<dim3(512), dim3(256), 0, stream>>>(x, Wth, Wtl, Qh, Ql, Kh, Kl, Vt);

  const size_t need16 = 5 * QB + 16 * (size_t)SLEN * 8 + 16 * (size_t)SLEN * 64 * 2;
  if (ws_size >= need16) {
    float* pML = (float*)tail;                                   // 16*8192*2 f32 = 1 MB
    unsigned short* pOn = (unsigned short*)(tail + 16 * (size_t)SLEN * 8);
    k_flash<16><<<dim3(32, 16), dim3(256), 0, stream>>>(Qh, Ql, Kh, Kl, Vt, pOn, pML);
    k_merge<16><<<dim3(1024), dim3(256), 0, stream>>>(pOn, pML, out);
  } else {
    float* pML = (float*)tail;                                   // 8*8192*2 f32 = 0.5 MB
    unsigned short* pOn = (unsigned short*)(tail + 8 * (size_t)SLEN * 8);
    k_flash<8><<<dim3(32, 8), dim3(256), 0, stream>>>(Qh, Ql, Kh, Kl, Vt, pOn, pML);
    k_merge<8><<<dim3(1024), dim3(256), 0, stream>>>(pOn, pML, out);
  }
}

// Round 9
// 98.098 us; speedup vs baseline: 3.2721x; 1.1450x over previous
//
#include <hip/hip_runtime.h>

#define SLEN 8192
#define DIN  512

typedef short bf16x8 __attribute__((ext_vector_type(8)));
typedef float f32x4  __attribute__((ext_vector_type(4)));
typedef float f32x16 __attribute__((ext_vector_type(16)));
typedef unsigned int u32x4 __attribute__((ext_vector_type(4)));
typedef unsigned int u32x2 __attribute__((ext_vector_type(2)));

__device__ __forceinline__ unsigned short f2bf(float f) {
  unsigned int u = __float_as_uint(f);
  u += 0x7FFFu + ((u >> 16) & 1u);           // RNE
  return (unsigned short)(u >> 16);
}
__device__ __forceinline__ float bf2f(unsigned short h) {
  return __uint_as_float(((unsigned int)h) << 16);
}
__device__ __forceinline__ unsigned int cvtpk(float lo, float hi) {
  unsigned int r;
  asm volatile("v_cvt_pk_bf16_f32 %0, %1, %2" : "=v"(r) : "v"(lo), "v"(hi));
  return r;
}

#define MFMA16(a, b, c) __builtin_amdgcn_mfma_f32_16x16x32_bf16((a), (b), (c), 0, 0, 0)
#define MFMA32(a, b, c) __builtin_amdgcn_mfma_f32_32x32x16_bf16((a), (b), (c), 0, 0, 0)

// XOR swizzle for [row][128B] LDS tiles (read side; write side = pre-swizzled global src)
__device__ __forceinline__ int SW(int row, int off) {
  return row * 128 + (off ^ ((row & 7) << 4));
}

// ------- B: split + transpose W -> Wt[n][k], n: 0-63 Q(scaled), 64-127 K, 128-191 V -------
__global__ __launch_bounds__(256) void k_splitw(const float* __restrict__ Wq,
                                                const float* __restrict__ Wk,
                                                const float* __restrict__ Wv,
                                                unsigned short* __restrict__ Wth,
                                                unsigned short* __restrict__ Wtl) {
  int idx = blockIdx.x * 256 + threadIdx.x;  // n*512 + k, 98304 total
  int n = idx >> 9, k = idx & 511;
  float w;
  if (n < 64)       w = Wq[k * 64 + n] * 0.18033688011112042f;  // log2(e)/8 folded in
  else if (n < 128) w = Wk[k * 64 + (n - 64)];
  else              w = Wv[k * 64 + (n - 128)];
  unsigned short h = f2bf(w);
  Wth[idx] = h;
  Wtl[idx] = f2bf(w - bf2f(h));
}

// ---------------- C: QKV = x @ [Wq|Wk|Wv], x read ONCE, 16-row m-tiles ----------------
__global__ __launch_bounds__(256) void k_qkv(const float* __restrict__ x,
                                             const unsigned short* __restrict__ Wth,
                                             const unsigned short* __restrict__ Wtl,
                                             unsigned short* __restrict__ Qh,
                                             unsigned short* __restrict__ Ql,
                                             unsigned short* __restrict__ Kh,
                                             unsigned short* __restrict__ Kl,
                                             unsigned short* __restrict__ Vt) {
  const int tid = threadIdx.x;
  const int wave = tid >> 6, lane = tid & 63;
  const int c = lane & 15, g = lane >> 4;
  const int mbase = blockIdx.x * 16;              // 512 m-tiles of 16 rows
  const int nt0 = wave * 3;                       // each wave: 3 of 12 n-tiles

  const int rowA = mbase + c;                     // all waves share rows (L1 broadcast)
  f32x4 acc[3];
  for (int j = 0; j < 3; ++j) acc[j] = (f32x4){0.f, 0.f, 0.f, 0.f};

  for (int k0 = 0; k0 < DIN; k0 += 32) {
    const float* xp = x + (size_t)rowA * DIN + k0 + g * 8;
    float4 f0 = *reinterpret_cast<const float4*>(xp);
    float4 f1 = *reinterpret_cast<const float4*>(xp + 4);
    float fv[8] = {f0.x, f0.y, f0.z, f0.w, f1.x, f1.y, f1.z, f1.w};
    bf16x8 ah, al;
#pragma unroll
    for (int j = 0; j < 8; ++j) {
      unsigned short h = f2bf(fv[j]);
      ah[j] = (short)h;
      al[j] = (short)f2bf(fv[j] - bf2f(h));
    }
#pragma unroll
    for (int j = 0; j < 3; ++j) {
      int ncol = (nt0 + j) * 16 + c;
      bf16x8 bh = *reinterpret_cast<const bf16x8*>(&Wth[ncol * DIN + k0 + g * 8]);
      bf16x8 bl = *reinterpret_cast<const bf16x8*>(&Wtl[ncol * DIN + k0 + g * 8]);
      acc[j] = MFMA16(ah, bh, acc[j]);
      acc[j] = MFMA16(ah, bl, acc[j]);
      acc[j] = MFMA16(al, bh, acc[j]);
    }
  }
  // C layout: col=lane&15, row=(lane>>4)*4+r  (16-row tile)
#pragma unroll
  for (int j = 0; j < 3; ++j) {
    int nt = nt0 + j;
    if (nt < 8) {
#pragma unroll
      for (int r = 0; r < 4; ++r) {
        int Rrow = mbase + g * 4 + r;
        float v = acc[j][r];
        unsigned short h = f2bf(v);
        unsigned short lo = f2bf(v - bf2f(h));
        if (nt < 4) {
          Qh[Rrow * 64 + nt * 16 + c] = h;
          Ql[Rrow * 64 + nt * 16 + c] = lo;
        } else {
          Kh[Rrow * 64 + (nt - 4) * 16 + c] = h;
          Kl[Rrow * 64 + (nt - 4) * 16 + c] = lo;
        }
      }
    } else {
      int np = nt * 16 + c - 128;
      int Rbase = mbase + g * 4;
      u32x2 pk;
      pk.x = cvtpk(acc[j][0], acc[j][1]);
      pk.y = cvtpk(acc[j][2], acc[j][3]);
      *reinterpret_cast<u32x2*>(&Vt[(size_t)np * SLEN + Rbase]) = pk;  // V^T [64][8192]
    }
  }
}

// ---------------- D: flash attention, swapped 32x32, DMA double-buffer staging ----------------
template <int NS>
__global__ __launch_bounds__(256, 2) void k_flash(const unsigned short* __restrict__ Qh,
                                                  const unsigned short* __restrict__ Ql,
                                                  const unsigned short* __restrict__ Kh,
                                                  const unsigned short* __restrict__ Kl,
                                                  const unsigned short* __restrict__ Vt,
                                                  unsigned short* __restrict__ pOn,
                                                  float* __restrict__ pML) {
  constexpr int KIT = 128 / NS;   // 64-key tiles per split
  __shared__ __align__(16) unsigned char smem[2 * 24576];   // dbuf {KH,KL,VT}
  const int tid = threadIdx.x;
  const int wave = tid >> 6, lane = tid & 63;
  const int q32 = lane & 31, hi = lane >> 5;
  const int qtile = blockIdx.x;   // 32 q-tiles of 256
  const int ks = blockIdx.y;

  // Q B-fragments: B[k=hi*8+j][col=q32], per (qs, kk): bf16x8 of own q-row
  int qrow[2];
  bf16x8 qfh[2][4], qfl[2][4];
#pragma unroll
  for (int qs = 0; qs < 2; ++qs) {
    qrow[qs] = qtile * 256 + wave * 64 + qs * 32 + q32;
#pragma unroll
    for (int kk = 0; kk < 4; ++kk) {
      qfh[qs][kk] = *reinterpret_cast<const bf16x8*>(&Qh[qrow[qs] * 64 + kk * 16 + hi * 8]);
      qfl[qs][kk] = *reinterpret_cast<const bf16x8*>(&Ql[qrow[qs] * 64 + kk * 16 + hi * 8]);
    }
  }
  bf16x8 ones8;
#pragma unroll
  for (int j = 0; j < 8; ++j) ones8[j] = (short)0x3F80;

  f32x16 o[2][2];
#pragma unroll
  for (int qs = 0; qs < 2; ++qs)
#pragma unroll
    for (int db = 0; db < 2; ++db)
#pragma unroll
      for (int r = 0; r < 16; ++r) o[qs][db][r] = 0.f;
  float m_run[2] = {-1e30f, -1e30f};
  float l_run[2] = {0.f, 0.f};

  // DMA staging: wave w covers chunks [w*6, w*6+6) of 24 x 1KB; lane lays its 16B at
  // base + lane*16 (HW). Global source col pre-swizzled so LDS[row][seg] = G[row][seg^(row&7)],
  // matching SW() on the read side (rule 21: linear dest + inverse-swizzled source).
  const int r8 = lane >> 3;
  const int ce = ((lane & 7) ^ r8) * 8;          // source col in elems (8 bf16 = 16B)
  auto STAGE = [&](int it, int bo) {
    const int kb = ks * (SLEN / NS) + it * 64;
#pragma unroll
    for (int u = 0; u < 6; ++u) {
      int ch = wave * 6 + u;
      int arr = ch >> 3;
      int row = (ch & 7) * 8 + r8;
      const unsigned short* src;
      if (arr == 0)      src = &Kh[(kb + row) * 64 + ce];
      else if (arr == 1) src = &Kl[(kb + row) * 64 + ce];
      else               src = &Vt[(size_t)row * SLEN + kb + ce];
      __builtin_amdgcn_global_load_lds(
          (const __attribute__((address_space(1))) unsigned int*)src,
          (__attribute__((address_space(3))) unsigned int*)(smem + bo + ch * 1024),
          16, 0, 0);
    }
  };

  int boff = 0;
  STAGE(0, 0);
  __syncthreads();                                // vmcnt(0): tile 0 landed

  for (int it = 0; it < KIT; ++it) {
    if (it + 1 < KIT) STAGE(it + 1, boff ^ 24576);   // next tile flies during compute
    unsigned char* KH = smem + boff;
    unsigned char* KL = KH + 8192;
    unsigned char* VT = KH + 16384;

#pragma unroll
    for (int s = 0; s < 2; ++s) {          // two 32-key subtiles
      bf16x8 kfh[4], kfl[4], vf[2][2];
#pragma unroll
      for (int kk = 0; kk < 4; ++kk) {
        kfh[kk] = *reinterpret_cast<const bf16x8*>(&KH[SW(32 * s + q32, 32 * kk + 16 * hi)]);
        kfl[kk] = *reinterpret_cast<const bf16x8*>(&KL[SW(32 * s + q32, 32 * kk + 16 * hi)]);
      }
#pragma unroll
      for (int db = 0; db < 2; ++db)
#pragma unroll
        for (int ch = 0; ch < 2; ++ch)
          vf[db][ch] = *reinterpret_cast<const bf16x8*>(&VT[SW(32 * db + q32, 64 * s + 32 * ch + 16 * hi)]);

#pragma unroll
      for (int qs = 0; qs < 2; ++qs) {
        // S^T = K·Q^T: D[k=crow(r,hi)][q=q32]
        f32x16 S;
#pragma unroll
        for (int r = 0; r < 16; ++r) S[r] = 0.f;
        __builtin_amdgcn_s_setprio(1);
#pragma unroll
        for (int kk = 0; kk < 4; ++kk) {
          S = MFMA32(kfh[kk], qfh[qs][kk], S);
          S = MFMA32(kfh[kk], qfl[qs][kk], S);
          S = MFMA32(kfl[kk], qfh[qs][kk], S);
        }
        __builtin_amdgcn_s_setprio(0);

        // lane-local row max (own 16 k) + cross-half combine
        float pm = S[0];
#pragma unroll
        for (int r = 1; r < 16; ++r) pm = fmaxf(pm, S[r]);
        pm = fmaxf(pm, __shfl_xor(pm, 32));
        if (!__all(pm - m_run[qs] <= 8.0f)) {   // defer-max (T13)
          float mnew = fmaxf(m_run[qs], pm);
          float alpha = exp2f(m_run[qs] - mnew);
#pragma unroll
          for (int db = 0; db < 2; ++db)
#pragma unroll
            for (int r = 0; r < 16; ++r) o[qs][db][r] *= alpha;
          l_run[qs] *= alpha;
          m_run[qs] = mnew;
        }
        float p[16];
#pragma unroll
        for (int r = 0; r < 16; ++r) p[r] = exp2f(S[r] - m_run[qs]);
        unsigned int W[8];
#pragma unroll
        for (int i = 0; i < 8; ++i) W[i] = cvtpk(p[2 * i], p[2 * i + 1]);
        // redistribute k-halves across lane halves -> PV B-fragments (T12)
        asm volatile("v_permlane32_swap_b32 %0, %1" : "+v"(W[0]), "+v"(W[2]));
        asm volatile("v_permlane32_swap_b32 %0, %1" : "+v"(W[1]), "+v"(W[3]));
        asm volatile("v_permlane32_swap_b32 %0, %1" : "+v"(W[4]), "+v"(W[6]));
        asm volatile("v_permlane32_swap_b32 %0, %1" : "+v"(W[5]), "+v"(W[7]));
        u32x4 pw0 = {W[0], W[1], W[2], W[3]};
        u32x4 pw1 = {W[4], W[5], W[6], W[7]};
        bf16x8 pb0 = *reinterpret_cast<bf16x8*>(&pw0);
        bf16x8 pb1 = *reinterpret_cast<bf16x8*>(&pw1);

        __builtin_amdgcn_s_setprio(1);
        f32x16 rs;
#pragma unroll
        for (int r = 0; r < 16; ++r) rs[r] = 0.f;
        rs = MFMA32(ones8, pb0, rs);            // rowsum[q] in every row
        rs = MFMA32(ones8, pb1, rs);
        // O^T[d][q] += V^T·P^T
        o[qs][0] = MFMA32(vf[0][0], pb0, o[qs][0]);
        o[qs][0] = MFMA32(vf[0][1], pb1, o[qs][0]);
        o[qs][1] = MFMA32(vf[1][0], pb0, o[qs][1]);
        o[qs][1] = MFMA32(vf[1][1], pb1, o[qs][1]);
        __builtin_amdgcn_s_setprio(0);
        l_run[qs] += rs[0];
      }
    }
    __syncthreads();     // vmcnt(0)+lgkmcnt(0)+barrier: next tile landed, cur buffer free
    boff ^= 24576;
  }

  // epilogue: normalized bf16 partials + (m,l)
#pragma unroll
  for (int qs = 0; qs < 2; ++qs) {
    float inv = 1.0f / l_run[qs];
#pragma unroll
    for (int db = 0; db < 2; ++db)
#pragma unroll
      for (int i = 0; i < 8; ++i) {
        unsigned int w = cvtpk(o[qs][db][2 * i] * inv, o[qs][db][2 * i + 1] * inv);
        int d = 2 * (i & 1) + 8 * (i >> 1) + 4 * hi + 32 * db;
        *reinterpret_cast<unsigned int*>(&pOn[((size_t)ks * SLEN + qrow[qs]) * 64 + d]) = w;
      }
    if (hi == 0) {
      pML[((size_t)ks * SLEN + qrow[qs]) * 2 + 0] = m_run[qs];
      pML[((size_t)ks * SLEN + qrow[qs]) * 2 + 1] = l_run[qs];
    }
  }
}

// ---------------- E: merge K-split partials (u32-pair vectorized) ----------------
template <int NS>
__global__ __launch_bounds__(256) void k_merge(const unsigned short* __restrict__ pOn,
                                               const float* __restrict__ pML,
                                               float* __restrict__ out) {
  int idx = blockIdx.x * 256 + threadIdx.x;  // 262144 u32-pairs
  int row = idx >> 5, dp = idx & 31;
  float ms[NS], ls[NS];
  float M = -1e30f;
#pragma unroll
  for (int s = 0; s < NS; ++s) {
    ms[s] = pML[((size_t)s * SLEN + row) * 2 + 0];
    ls[s] = pML[((size_t)s * SLEN + row) * 2 + 1];
    M = fmaxf(M, ms[s]);
  }
  float Wsum = 0.f, O0 = 0.f, O1 = 0.f;
  const unsigned int* pOn32 = reinterpret_cast<const unsigned int*>(pOn);
#pragma unroll
  for (int s = 0; s < NS; ++s) {
    float w = ls[s] * exp2f(ms[s] - M);
    unsigned int v = pOn32[((size_t)s * SLEN + row) * 32 + dp];
    O0 += w * bf2f((unsigned short)(v & 0xFFFF));
    O1 += w * bf2f((unsigned short)(v >> 16));
    Wsum += w;
  }
  float inv = 1.0f / Wsum;
  float2 res = {O0 * inv, O1 * inv};
  *reinterpret_cast<float2*>(&out[(size_t)row * 64 + dp * 2]) = res;
}

extern "C" void kernel_launch(void* const* d_in, const int* in_sizes, int n_in,
                              void* d_out, int out_size, void* d_ws, size_t ws_size,
                              hipStream_t stream) {
  const float* x  = (const float*)d_in[0];
  const float* Wq = (const float*)d_in[1];
  const float* Wk = (const float*)d_in[2];
  const float* Wv = (const float*)d_in[3];
  float* out = (float*)d_out;

  char* w = (char*)d_ws;
  const size_t QB = (size_t)SLEN * 64 * 2;       // 1,048,576 per buffer
  unsigned short* Qh = (unsigned short*)w;
  unsigned short* Ql = Qh + SLEN * 64;
  unsigned short* Kh = Ql + SLEN * 64;
  unsigned short* Kl = Kh + SLEN * 64;
  unsigned short* Vt = Kl + SLEN * 64;
  char* tail = w + 5 * QB;                       // 5,242,880
  // W lives in [tail, tail+393216): dead once k_qkv finishes; pML overlays it later
  unsigned short* Wth = (unsigned short*)tail;
  unsigned short* Wtl = Wth + 192 * DIN;

  k_splitw<<<dim3(384), dim3(256), 0, stream>>>(Wq, Wk, Wv, Wth, Wtl);
  k_qkv<<<dim3(512), dim3(256), 0, stream>>>(x, Wth, Wtl, Qh, Ql, Kh, Kl, Vt);

  const size_t need16 = 5 * QB + 16 * (size_t)SLEN * 8 + 16 * (size_t)SLEN * 64 * 2;
  if (ws_size >= need16) {
    float* pML = (float*)tail;                                   // 16*8192*2 f32 = 1 MB
    unsigned short* pOn = (unsigned short*)(tail + 16 * (size_t)SLEN * 8);
    k_flash<16><<<dim3(32, 16), dim3(256), 0, stream>>>(Qh, Ql, Kh, Kl, Vt, pOn, pML);
    k_merge<16><<<dim3(1024), dim3(256), 0, stream>>>(pOn, pML, out);
  } else {
    float* pML = (float*)tail;                                   // 8*8192*2 f32 = 0.5 MB
    unsigned short* pOn = (unsigned short*)(tail + 8 * (size_t)SLEN * 8);
    k_flash<8><<<dim3(32, 8), dim3(256), 0, stream>>>(Qh, Ql, Kh, Kl, Vt, pOn, pML);
    k_merge<8><<<dim3(1024), dim3(256), 0, stream>>>(pOn, pML, out);
  }
}